// Round 8
// baseline (290.666 us; speedup 1.0000x reference)
//
#include <hip/hip_runtime.h>

#define DIMB 2
#define DIMS 192
#define DPT 4        // d-outputs per thread
#define TX 48        // threads in d: 48*4 = 192 (FULL d extent -> no block d-edges)
#define TY 8         // w rows per block
#define HCHUNK 6     // output h rows per block

// One plane of raw data for this thread: 3 w-rows x float4 (d0..d0+3), both
// arrays. 24 VGPRs. d-window edges (d0-1, d0+4) come from lane+-1 shuffles at
// consume time; global d boundaries are exact zeros (tx==0 / tx==47 masks).
// No scalar edge loads anywhere -> slim enough to double-buffer w/o spilling
// (R3/R4 spilled at 36-float buffers + 3 P-planes).
struct Buf { float4 p[3]; float4 t[3]; };

__device__ __forceinline__ void load_plane(
    const float* __restrict__ pred, const float* __restrict__ targ,
    int b, int hh, int w, int tx, Buf& B)
{
    const bool hok = (hh >= 0) & (hh < DIMS);
    const int hc = hok ? hh : 0;
#pragma unroll
    for (int r = 0; r < 3; ++r) {
        const int wc = w - 1 + r;
        const bool ok = hok & (wc >= 0) & (wc < DIMS);
        const size_t base =
            (((size_t)b * DIMS + hc) * DIMS + (ok ? wc : 0)) * DIMS + 4 * tx;
        float4 pz = {0.f, 0.f, 0.f, 0.f}, tz = {0.f, 0.f, 0.f, 0.f};
        if (ok) {
            pz = *reinterpret_cast<const float4*>(pred + base);
            tz = *reinterpret_cast<const float4*>(targ + base);
        }
        B.p[r] = pz;
        B.t[r] = tz;
    }
}

// 3x3 (w,d)-plane sums of the 5 product channels. Branchless: OOB rows are
// zeros, which contribute exactly the reference's zero padding.
__device__ __forceinline__ void consume(const Buf& B, int tx, float (&P)[5][DPT])
{
#pragma unroll
    for (int c = 0; c < 5; ++c)
#pragma unroll
        for (int j = 0; j < DPT; ++j) P[c][j] = 0.f;
#pragma unroll
    for (int r = 0; r < 3; ++r) {
        const float4 mp = B.p[r], mt = B.t[r];
        float p0 = __shfl_up(mp.w, 1, 64);
        float t0 = __shfl_up(mt.w, 1, 64);
        float p5 = __shfl_down(mp.x, 1, 64);
        float t5 = __shfl_down(mt.x, 1, 64);
        p0 = (tx == 0)      ? 0.f : p0;   // global d=-1 pad
        t0 = (tx == 0)      ? 0.f : t0;
        p5 = (tx == TX - 1) ? 0.f : p5;   // global d=192 pad
        t5 = (tx == TX - 1) ? 0.f : t5;
        const float pv[6] = {p0, mp.x, mp.y, mp.z, mp.w, p5};
        const float tv[6] = {t0, mt.x, mt.y, mt.z, mt.w, t5};
        float pp[6], tt[6], pt[6];
#pragma unroll
        for (int k = 0; k < 6; ++k) {
            pp[k] = pv[k] * pv[k];
            tt[k] = tv[k] * tv[k];
            pt[k] = pv[k] * tv[k];
        }
#pragma unroll
        for (int j = 0; j < DPT; ++j) {
            P[0][j] += pv[j] + pv[j+1] + pv[j+2];
            P[1][j] += tv[j] + tv[j+1] + tv[j+2];
            P[2][j] += pp[j] + pp[j+1] + pp[j+2];
            P[3][j] += tt[j] + tt[j+1] + tt[j+2];
            P[4][j] += pt[j] + pt[j+1] + pt[j+2];
        }
    }
}

__device__ __forceinline__ float ncc_row3(const float (&Pm)[5][DPT],
                                          const float (&Pc)[5][DPT],
                                          const float (&Pn)[5][DPT])
{
    const float inv = 1.0f / 27.0f;
    float acc = 0.f;
#pragma unroll
    for (int j = 0; j < DPT; ++j) {
        const float sI  = Pm[0][j] + Pc[0][j] + Pn[0][j];
        const float sJ  = Pm[1][j] + Pc[1][j] + Pn[1][j];
        const float sII = Pm[2][j] + Pc[2][j] + Pn[2][j];
        const float sJJ = Pm[3][j] + Pc[3][j] + Pn[3][j];
        const float sIJ = Pm[4][j] + Pc[4][j] + Pn[4][j];
        const float uI = sI * inv;
        const float uJ = sJ * inv;
        const float cross = sIJ - uI * sJ;
        const float pvar  = sII - uI * sI;
        const float tvar  = sJJ - uJ * sJ;
        acc += (cross * cross) * __builtin_amdgcn_rcpf(tvar * pvar + 1e-5f);
    }
    return acc;
}

__global__ __launch_bounds__(384, 3)
void FusedLocalNormalizedCrossCorrelationLoss_37838661877790_kernel(
    const float* __restrict__ pred, const float* __restrict__ targ,
    double* __restrict__ acc_out)
{
    const int tx = threadIdx.x;              // 48 d-quads (full d)
    const int ty = threadIdx.y;              // 8 w rows
    const int w  = blockIdx.y * TY + ty;
    const int bz = blockIdx.z;
    const int b  = bz >> 5;                  // 2 batches
    const int h0 = (bz & 31) * HCHUNK;       // 32 h-chunks

    Buf A, Bf;
    float P0[5][DPT], P1[5][DPT], P2[5][DPT];
    float acc = 0.f;

    // Barrier-free per-wave pipeline: load(q+2) issued right after consume(q)
    // frees its buffer; each load is in flight for one full plane-compute.
    // All roles are static names -- nothing can be demoted to scratch.
    load_plane(pred, targ, b, h0 - 1, w, tx, A);
    load_plane(pred, targ, b, h0,     w, tx, Bf);

    consume(A, tx, P0);
    load_plane(pred, targ, b, h0 + 1, w, tx, A);
    consume(Bf, tx, P1);
    load_plane(pred, targ, b, h0 + 2, w, tx, Bf);

    consume(A, tx, P2);  acc += ncc_row3(P0, P1, P2);
    load_plane(pred, targ, b, h0 + 3, w, tx, A);
    consume(Bf, tx, P0); acc += ncc_row3(P1, P2, P0);
    load_plane(pred, targ, b, h0 + 4, w, tx, Bf);
    consume(A, tx, P1);  acc += ncc_row3(P2, P0, P1);
    load_plane(pred, targ, b, h0 + 5, w, tx, A);
    consume(Bf, tx, P2); acc += ncc_row3(P0, P1, P2);
    load_plane(pred, targ, b, h0 + 6, w, tx, Bf);
    consume(A, tx, P0);  acc += ncc_row3(P1, P2, P0);
    consume(Bf, tx, P1); acc += ncc_row3(P2, P0, P1);

    // Reduction: wave shuffle tree -> LDS -> one fp64 atomic per block.
#pragma unroll
    for (int off = 32; off > 0; off >>= 1)
        acc += __shfl_down(acc, off, 64);
    __shared__ float wacc[6];
    const int tid = ty * TX + tx;
    if ((tid & 63) == 0) wacc[tid >> 6] = acc;
    __syncthreads();
    if (tid == 0) {
        double s = 0.0;
#pragma unroll
        for (int i = 0; i < 6; ++i) s += (double)wacc[i];
        atomicAdd(acc_out, s);
    }
}

__global__ void ncc_finalize(const double* __restrict__ acc,
                             float* __restrict__ out)
{
    const double n = (double)((size_t)DIMB * DIMS * DIMS * DIMS);
    out[0] = (float)(-acc[0] / n);
}

extern "C" void kernel_launch(void* const* d_in, const int* in_sizes, int n_in,
                              void* d_out, int out_size, void* d_ws, size_t ws_size,
                              hipStream_t stream) {
    const float* pred = (const float*)d_in[0];
    const float* targ = (const float*)d_in[1];
    double* acc = (double*)d_ws;

    hipMemsetAsync(d_ws, 0, sizeof(double), stream);

    dim3 block(TX, TY, 1);
    dim3 grid(1, DIMS / TY, DIMB * (DIMS / HCHUNK));   // 1 x 24 x 64 = 1536
    FusedLocalNormalizedCrossCorrelationLoss_37838661877790_kernel
        <<<grid, block, 0, stream>>>(pred, targ, acc);
    ncc_finalize<<<1, 1, 0, stream>>>(acc, (float*)d_out);
}